// Round 13
// baseline (1177.021 us; speedup 1.0000x reference)
//
#include <hip/hip_runtime.h>
#include <hip/hip_bf16.h>
#include <cstdint>
#include <cstddef>

#define MAX_K 70
#define BN_EPS 1e-5f
#define KPAD 360   // 352 data + 8 pad bf16 -> stride 720B, 2-way max bank alias
#define NPOOL 16   // pool copies to spread atomic contention

typedef __attribute__((ext_vector_type(4))) float f32x4;
typedef __attribute__((ext_vector_type(8))) short bf16x8;
typedef __attribute__((ext_vector_type(4))) int i32x4;

// ---------------- load/store helpers (f32 or bf16 storage) ----------------
__device__ inline float loadv(const float* p, size_t i) { return p[i]; }
__device__ inline float loadv(const __hip_bfloat16* p, size_t i) {
    return __bfloat162float(p[i]);
}
__device__ inline void storev(float* p, size_t i, float v) { p[i] = v; }
__device__ inline void storev(__hip_bfloat16* p, size_t i, float v) {
    p[i] = __float2bfloat16(v);
}
__device__ inline float bf2f(unsigned short u) {
    union { unsigned int i; float f; } x; x.i = ((unsigned int)u) << 16; return x.f;
}
__device__ inline unsigned short f2bfu(float f) {
    __hip_bfloat16 h = __float2bfloat16(f);
    return *reinterpret_cast<unsigned short*>(&h);
}

// ---- per-block BN scale/shift derivation from accumulated sum/sumsq ------
template <int FO>
__device__ inline void bn_make(const double* __restrict__ ds,
                               const double* __restrict__ dq,
                               const float* __restrict__ g,
                               const float* __restrict__ be, int C,
                               float* aSs, float* cSs, int tid) {
    if (tid < FO) {
        double m = ds[tid] / (double)C;
        double v = dq[tid] / (double)C - m * m;
        float rs = rsqrtf((float)v + BN_EPS);
        float a = g[tid] * rs;
        aSs[tid] = a;
        cSs[tid] = be[tid] - (float)m * a;
    }
}

// ---------------------------------------------------------------- utilities
__global__ void zero_kernel(float* __restrict__ p, size_t n) {
    size_t i = (size_t)blockIdx.x * blockDim.x + threadIdx.x;
    size_t stride = (size_t)gridDim.x * blockDim.x;
    for (; i < n; i += stride) p[i] = 0.f;
}

// ---------------- stage 1a: histogram (XCD-partitioned by ccid range) -----
__global__ __launch_bounds__(256) void hist_kernel(
    const i32x4* __restrict__ cc4, int* __restrict__ cnt, int n4, int cg) {
    int g  = blockIdx.x & 7;
    int k  = blockIdx.x >> 3;
    int nk = gridDim.x >> 3;
    int clo = g * cg, chi = clo + cg;
    for (int q = k * 256 + threadIdx.x; q < n4; q += nk * 256) {
        i32x4 v = cc4[q];
        #pragma unroll
        for (int e = 0; e < 4; ++e) {
            int c = v[e];
            if (c >= clo && c < chi) atomicAdd(&cnt[c], 1);
        }
    }
}

// --------------------------------------- stage 1b: exclusive scan over cnt
__global__ __launch_bounds__(256) void scan_partial(const int* __restrict__ cnt,
                                                    int* __restrict__ bsum, int C) {
    __shared__ int sc[256];
    int b = blockIdx.x, tid = threadIdx.x;
    int base = b * 2048 + tid * 8;
    int t = 0;
    #pragma unroll
    for (int e = 0; e < 8; ++e) {
        int c = base + e;
        t += (c < C) ? cnt[c] : 0;
    }
    sc[tid] = t;
    __syncthreads();
    for (int o = 128; o > 0; o >>= 1) {
        if (tid < o) sc[tid] += sc[tid + o];
        __syncthreads();
    }
    if (tid == 0) bsum[b] = sc[0];
}

__global__ void scan_tops(int* __restrict__ bsum, int nb) {
    if (blockIdx.x == 0 && threadIdx.x == 0) {
        int run = 0;
        for (int k = 0; k < nb; ++k) { int t = bsum[k]; bsum[k] = run; run += t; }
    }
}

__global__ __launch_bounds__(256) void scan_final(const int* __restrict__ cnt,
                                                  const int* __restrict__ btop,
                                                  int* __restrict__ off,
                                                  int* __restrict__ woff, int C) {
    __shared__ int sc[256];
    int b = blockIdx.x, tid = threadIdx.x;
    int base = b * 2048 + tid * 8;
    int v[8];
    int tsum = 0;
    #pragma unroll
    for (int e = 0; e < 8; ++e) {
        int c = base + e;
        v[e] = (c < C) ? cnt[c] : 0;
        tsum += v[e];
    }
    sc[tid] = tsum;
    __syncthreads();
    for (int d = 1; d < 256; d <<= 1) {
        int t = (tid >= d) ? sc[tid - d] : 0;
        __syncthreads();
        sc[tid] += t;
        __syncthreads();
    }
    int run = btop[b] + sc[tid] - tsum;
    #pragma unroll
    for (int e = 0; e < 8; ++e) {
        int c = base + e;
        if (c < C) { off[c] = run; woff[c] = run; }
        run += v[e];
    }
}

// ------- prep: feat -> 16B records {idx:int, f0..f4:bf16, pad} (coalesced)
__global__ __launch_bounds__(256) void conv_kernel(
    const float* __restrict__ feat, i32x4* __restrict__ rec, int N) {
    int i = blockIdx.x * 256 + threadIdx.x;
    int stride = gridDim.x * 256;
    for (; i < N; i += stride) {
        const float* fp = &feat[(size_t)i * 5];
        unsigned int h0 = f2bfu(fp[0]), h1 = f2bfu(fp[1]), h2 = f2bfu(fp[2]);
        unsigned int h3 = f2bfu(fp[3]), h4 = f2bfu(fp[4]);
        i32x4 r;
        r[0] = i;
        r[1] = (int)(h0 | (h1 << 16));
        r[2] = (int)(h2 | (h3 << 16));
        r[3] = (int)h4;
        rec[i] = r;
    }
}

// ----- stage 1c: XCD-partitioned counting-sort scatter of 16B records.
// rec reads are NON-TEMPORAL: each record is consumed exactly once per
// launch, so caching them in L2 is pure pollution that evicts the ~1.6MB
// of partially-filled srec write-head lines. ccids keeps normal caching
// (L3-resident, 8x reuse).
__global__ __launch_bounds__(256) void scatter2p_kernel(
    const i32x4* __restrict__ ccids4, const i32x4* __restrict__ rec,
    int* __restrict__ woff, i32x4* __restrict__ srec, int n4, int cg) {
    int g   = blockIdx.x & 7;
    int k   = blockIdx.x >> 3;
    int nk  = gridDim.x >> 3;
    int clo = g * cg, chi = clo + cg;
    for (int q = k * 256 + threadIdx.x; q < n4; q += nk * 256) {
        i32x4 v = ccids4[q];
        int base = q * 4;
        #pragma unroll
        for (int e = 0; e < 4; ++e) {
            int c = v[e];
            if (c >= clo && c < chi) {
                int p = atomicAdd(&woff[c], 1);
                srec[p] = __builtin_nontemporal_load(&rec[base + e]);
            }
        }
    }
}

// ----- prep: W4 -> bf16 w4t[256][128]; W1 -> bf16 w1t[32][352] (transposed)
__global__ void prep_kernel(const float* __restrict__ W4,
                            const float* __restrict__ W1,
                            unsigned short* __restrict__ w4t,
                            unsigned short* __restrict__ w1t) {
    int idx = blockIdx.x * 256 + threadIdx.x;
    if (idx < 32768) {
        int n = idx >> 7, k = idx & 127;
        w4t[idx] = f2bfu(W4[k * 256 + n]);
    } else if (idx < 32768 + 32 * 352) {
        int j = idx - 32768;
        int ch = j / 352, k = j - ch * 352;
        w1t[j] = (k < 350) ? f2bfu(W1[k * 32 + ch]) : 0;
    }
}

// --- stage 1d+2a: rank+pack+MFMA GEMM 350->32, COALESCED reads, BN1 stats --
// 4 waves/block, each wave owns 16 components (one 16-row MFMA A-tile)
__global__ __launch_bounds__(256) void layer1_mfma(
    const i32x4* __restrict__ srec, const int* __restrict__ cnt,
    const int* __restrict__ off,
    const unsigned short* __restrict__ w1t, const float* __restrict__ b1,
    float* __restrict__ z1, double* __restrict__ dsum,
    double* __restrict__ dsq, int C) {
    __shared__ unsigned short xtile[4][16][KPAD];  // 45 KB
    __shared__ float sps[4][32], spq[4][32];
    int tid  = threadIdx.x;
    int w    = tid >> 6;
    int lane = tid & 63;
    int cbase = blockIdx.x * 64 + w * 16;

    // zero my wave's tile
    unsigned int* xz = (unsigned int*)&xtile[w][0][0];
    for (int t = lane; t < 16 * (KPAD / 2); t += 64) xz[t] = 0u;

    // per-sub lengths/bases: lanes 0..15 carry subs 0..15
    int myc = 0, myo = 0;
    {
        int comp = cbase + (lane & 15);
        if (comp < C) { myc = cnt[comp]; myo = off[comp]; }
    }
    int fl[16], bs[16];
    #pragma unroll
    for (int s = 0; s < 16; ++s) {
        fl[s] = __shfl(myc, s);
        bs[s] = __shfl(myo, s);
    }
    // coalesced record loads: idx + feats in ONE int4 per member
    #pragma unroll
    for (int s = 0; s < 16; ++s) {
        if (fl[s] <= 64) {
            i32x4 r;
            int my = 0x7FFFFFFF;
            if (lane < fl[s]) {
                r = srec[bs[s] + lane];
                my = r[0];
            }
            // rank via shfl (VALU only)
            int rk = 0;
            for (int j = 0; j < fl[s]; ++j) {
                int o = __shfl(my, j);
                rk += (o < my) ? 1 : 0;
            }
            if (lane < fl[s]) {
                unsigned short* xp = &xtile[w][s][rk * 5];
                unsigned int y1 = (unsigned int)r[1];
                unsigned int y2 = (unsigned int)r[2];
                unsigned int y3 = (unsigned int)r[3];
                xp[0] = (unsigned short)(y1 & 0xffff);
                xp[1] = (unsigned short)(y1 >> 16);
                xp[2] = (unsigned short)(y2 & 0xffff);
                xp[3] = (unsigned short)(y2 >> 16);
                xp[4] = (unsigned short)(y3 & 0xffff);
            }
        } else {
            // rare fallback (cnt>64): rank via global records
            for (int e = lane; e < fl[s]; e += 64) {
                i32x4 r = srec[bs[s] + e];
                int my = r[0];
                int rk = 0;
                for (int j = 0; j < fl[s]; ++j)
                    rk += (srec[bs[s] + j][0] < my) ? 1 : 0;
                if (rk < MAX_K) {
                    unsigned short* xp = &xtile[w][s][rk * 5];
                    unsigned int y1 = (unsigned int)r[1];
                    unsigned int y2 = (unsigned int)r[2];
                    unsigned int y3 = (unsigned int)r[3];
                    xp[0] = (unsigned short)(y1 & 0xffff);
                    xp[1] = (unsigned short)(y1 >> 16);
                    xp[2] = (unsigned short)(y2 & 0xffff);
                    xp[3] = (unsigned short)(y2 >> 16);
                    xp[4] = (unsigned short)(y3 & 0xffff);
                }
            }
        }
    }
    __syncthreads();  // xtile writes -> cross-lane MFMA fragment reads

    int l15 = lane & 15, l4 = lane >> 4;
    f32x4 acc0 = {0.f, 0.f, 0.f, 0.f};
    f32x4 acc1 = {0.f, 0.f, 0.f, 0.f};
    const unsigned short* xbase = &xtile[w][l15][0];
    #pragma unroll
    for (int ks = 0; ks < 11; ++ks) {
        int k0 = ks * 32 + l4 * 8;
        bf16x8 a  = *(const bf16x8*)&xbase[k0];
        bf16x8 b0 = *(const bf16x8*)&w1t[(size_t)l15 * 352 + k0];
        bf16x8 bv = *(const bf16x8*)&w1t[(size_t)(16 + l15) * 352 + k0];
        acc0 = __builtin_amdgcn_mfma_f32_16x16x32_bf16(a, b0, acc0, 0, 0, 0);
        acc1 = __builtin_amdgcn_mfma_f32_16x16x32_bf16(a, bv, acc1, 0, 0, 0);
    }
    float bias0 = b1[l15];
    float bias1 = b1[16 + l15];
    float s0 = 0.f, q0 = 0.f, s1 = 0.f, q1 = 0.f;
    #pragma unroll
    for (int r = 0; r < 4; ++r) {
        int comp = cbase + l4 * 4 + r;
        if (comp < C) {
            float z0 = acc0[r] + bias0;
            float z1v = acc1[r] + bias1;
            z1[(size_t)comp * 32 + l15]      = z0;
            z1[(size_t)comp * 32 + 16 + l15] = z1v;
            s0 += z0; q0 += z0 * z0;
            s1 += z1v; q1 += z1v * z1v;
        }
    }
    // reduce over the 4 row-groups (lanes same l15, l4 in 0..3)
    s0 += __shfl_xor(s0, 16); s0 += __shfl_xor(s0, 32);
    q0 += __shfl_xor(q0, 16); q0 += __shfl_xor(q0, 32);
    s1 += __shfl_xor(s1, 16); s1 += __shfl_xor(s1, 32);
    q1 += __shfl_xor(q1, 16); q1 += __shfl_xor(q1, 32);
    if (lane < 16) {
        sps[w][l15] = s0;      spq[w][l15] = q0;
        sps[w][16 + l15] = s1; spq[w][16 + l15] = q1;
    }
    __syncthreads();
    if (tid < 32) {
        float s = sps[0][tid] + sps[1][tid] + sps[2][tid] + sps[3][tid];
        float q = spq[0][tid] + spq[1][tid] + spq[2][tid] + spq[3][tid];
        unsafeAtomicAdd(&dsum[tid], (double)s);
        unsafeAtomicAdd(&dsq[tid],  (double)q);
    }
}

// ---- generic layer: zout = relu(bn(zin)) @ W + b, BN derived per block ----
template <typename TI, typename TO, int FI, int FO, int CT, int RT>
__global__ __launch_bounds__(256) void layer_kernel(
    const TI* __restrict__ zin, const float* __restrict__ W,
    const float* __restrict__ bias,
    const double* __restrict__ dsI, const double* __restrict__ dqI,
    const float* __restrict__ g, const float* __restrict__ be,
    TO* __restrict__ zout,
    double* __restrict__ dsO, double* __restrict__ dqO, int C) {
    constexpr int CHG  = FO / CT;
    constexpr int NSUB = 256 / CHG;
    constexpr int R    = NSUB * RT;
    __shared__ float h[R][FI + 1];
    __shared__ float sps[NSUB * FO];
    __shared__ float spq[NSUB * FO];
    __shared__ float aSs[FI], cSs[FI];
    int tid = threadIdx.x;
    int c0 = blockIdx.x * R;
    bn_make<FI>(dsI, dqI, g, be, C, aSs, cSs, tid);
    __syncthreads();
    for (int t = tid; t < R * FI; t += 256) {
        int r = t / FI, k = t % FI;
        int c = c0 + r;
        float v = (c < C) ? loadv(zin, (size_t)c * FI + k) : 0.f;
        h[r][k] = fmaxf(fmaf(aSs[k], v, cSs[k]), 0.f);
    }
    __syncthreads();
    int cg  = tid % CHG;
    int sub = tid / CHG;
    int chbase = cg * CT;
    float acc[RT][CT];
    #pragma unroll
    for (int i = 0; i < RT; ++i)
        #pragma unroll
        for (int j = 0; j < CT; ++j) acc[i][j] = 0.f;
    for (int k = 0; k < FI; ++k) {
        float wv[CT];
        #pragma unroll
        for (int j4 = 0; j4 < CT; j4 += 4) {
            const float4 wq = *reinterpret_cast<const float4*>(
                &W[(size_t)k * FO + chbase + j4]);
            wv[j4 + 0] = wq.x; wv[j4 + 1] = wq.y;
            wv[j4 + 2] = wq.z; wv[j4 + 3] = wq.w;
        }
        #pragma unroll
        for (int i = 0; i < RT; ++i) {
            float hv = h[sub * RT + i][k];
            #pragma unroll
            for (int j = 0; j < CT; ++j) acc[i][j] = fmaf(hv, wv[j], acc[i][j]);
        }
    }
    float ps[CT], pq[CT];
    #pragma unroll
    for (int j = 0; j < CT; ++j) { ps[j] = 0.f; pq[j] = 0.f; }
    #pragma unroll
    for (int i = 0; i < RT; ++i) {
        int c = c0 + sub * RT + i;
        if (c < C) {
            #pragma unroll
            for (int j = 0; j < CT; ++j) {
                float z = acc[i][j] + bias[chbase + j];
                storev(zout, (size_t)c * FO + chbase + j, z);
                ps[j] += z;
                pq[j] += z * z;
            }
        }
    }
    #pragma unroll
    for (int j = 0; j < CT; ++j) {
        sps[sub * FO + chbase + j] = ps[j];
        spq[sub * FO + chbase + j] = pq[j];
    }
    __syncthreads();
    if (tid < FO) {
        float s = 0.f, q = 0.f;
        #pragma unroll
        for (int s2 = 0; s2 < NSUB; ++s2) {
            s += sps[s2 * FO + tid];
            q += spq[s2 * FO + tid];
        }
        unsafeAtomicAdd(&dsO[tid], (double)s);
        unsafeAtomicAdd(&dqO[tid], (double)q);
    }
}

// ------------- layer 4 via MFMA: z4 = relu(bn3(z3)) @ W4 + b4, fused stats
__global__ __launch_bounds__(256) void layer4_mfma(
    const __hip_bfloat16* __restrict__ z3, const unsigned short* __restrict__ w4t,
    const float* __restrict__ b4,
    const double* __restrict__ dsI, const double* __restrict__ dqI,
    const float* __restrict__ g, const float* __restrict__ be,
    __hip_bfloat16* __restrict__ z4,
    double* __restrict__ dsum, double* __restrict__ dsq, int C) {
    __shared__ float sps[2][256];
    __shared__ float spq[2][256];
    __shared__ float aSs[128], cSs[128];
    int tid = threadIdx.x, wid = tid >> 6, lane = tid & 63;
    int wm = wid >> 1, wn = wid & 1;
    int c0 = blockIdx.x * 64;
    int l15 = lane & 15, l4 = lane >> 4;
    const unsigned short* z3u = (const unsigned short*)z3;
    bn_make<128>(dsI, dqI, g, be, C, aSs, cSs, tid);
    __syncthreads();

    f32x4 acc[2][8];
    #pragma unroll
    for (int mi = 0; mi < 2; ++mi)
        #pragma unroll
        for (int ni = 0; ni < 8; ++ni) acc[mi][ni] = (f32x4){0.f, 0.f, 0.f, 0.f};

    int rowA0 = c0 + wm * 32 + l15;
    #pragma unroll
    for (int ks = 0; ks < 4; ++ks) {
        int k0 = ks * 32 + l4 * 8;
        float sc[8], cc[8];
        #pragma unroll
        for (int j = 0; j < 8; ++j) { sc[j] = aSs[k0 + j]; cc[j] = cSs[k0 + j]; }
        bf16x8 afrag[2];
        #pragma unroll
        for (int mi = 0; mi < 2; ++mi) {
            int r = rowA0 + mi * 16;
            int rc = (r < C) ? r : (C - 1);
            bf16x8 raw = *(const bf16x8*)&z3u[(size_t)rc * 128 + k0];
            bf16x8 af;
            #pragma unroll
            for (int j = 0; j < 8; ++j) {
                float v = bf2f((unsigned short)raw[j]);
                float hx = fmaxf(fmaf(sc[j], v, cc[j]), 0.f);
                af[j] = (short)f2bfu((r < C) ? hx : 0.f);
            }
            afrag[mi] = af;
        }
        bf16x8 bfrag[8];
        #pragma unroll
        for (int ni = 0; ni < 8; ++ni) {
            int n = wn * 128 + ni * 16 + l15;
            bfrag[ni] = *(const bf16x8*)&w4t[(size_t)n * 128 + k0];
        }
        #pragma unroll
        for (int mi = 0; mi < 2; ++mi)
            #pragma unroll
            for (int ni = 0; ni < 8; ++ni)
                acc[mi][ni] = __builtin_amdgcn_mfma_f32_16x16x32_bf16(
                    afrag[mi], bfrag[ni], acc[mi][ni], 0, 0, 0);
    }
    unsigned short* z4u = (unsigned short*)z4;
    #pragma unroll
    for (int ni = 0; ni < 8; ++ni) {
        int col = wn * 128 + ni * 16 + l15;
        float bv = b4[col];
        float s = 0.f, q = 0.f;
        #pragma unroll
        for (int mi = 0; mi < 2; ++mi) {
            #pragma unroll
            for (int r = 0; r < 4; ++r) {
                int row = c0 + wm * 32 + mi * 16 + l4 * 4 + r;
                float z = acc[mi][ni][r] + bv;
                if (row < C) {
                    z4u[(size_t)row * 256 + col] = f2bfu(z);
                    s += z;
                    q += z * z;
                }
            }
        }
        s += __shfl_xor(s, 16); s += __shfl_xor(s, 32);
        q += __shfl_xor(q, 16); q += __shfl_xor(q, 32);
        if (lane < 16) { sps[wm][col] = s; spq[wm][col] = q; }
    }
    __syncthreads();
    if (tid < 256) {
        float s = sps[0][tid] + sps[1][tid];
        float q = spq[0][tid] + spq[1][tid];
        unsafeAtomicAdd(&dsum[tid], (double)s);
        unsafeAtomicAdd(&dsq[tid],  (double)q);
    }
}

// ----------------------------------------------- per-image component counts
__global__ void imgcnt_kernel(const int* __restrict__ imgid,
                              int* __restrict__ pcnt, int C, int B) {
    __shared__ int scnt[64];
    int tid = threadIdx.x;
    if (tid < B) scnt[tid] = 0;
    __syncthreads();
    for (int i = blockIdx.x * 256 + tid; i < C; i += gridDim.x * 256)
        atomicAdd(&scnt[imgid[i]], 1);
    __syncthreads();
    if (tid < B) atomicAdd(&pcnt[tid], scnt[tid]);
}

// -- segment-sum of relu(bn4(z4)) into NPOOL pool copies (spread atomics) --
__global__ __launch_bounds__(256) void pool_kernel(
    const __hip_bfloat16* __restrict__ z4, const int* __restrict__ imgid,
    const double* __restrict__ dsI, const double* __restrict__ dqI,
    const float* __restrict__ g, const float* __restrict__ be,
    float* __restrict__ pool, int C, int B) {
    __shared__ float spool[64 * 256];
    __shared__ float aSs[256], cSs[256];
    int tid = threadIdx.x;
    int nb = B * 256;
    bn_make<256>(dsI, dqI, g, be, C, aSs, cSs, tid);
    for (int t = tid; t < nb; t += 256) spool[t] = 0.f;
    __syncthreads();
    float a = aSs[tid], cc = cSs[tid];
    int per  = (C + gridDim.x - 1) / gridDim.x;
    int cbeg = blockIdx.x * per;
    int cend = min(cbeg + per, C);
    for (int c = cbeg; c < cend; ++c) {
        int img = imgid[c];
        float v = loadv(z4, (size_t)c * 256 + tid);
        float hv = fmaxf(fmaf(a, v, cc), 0.f);
        spool[img * 256 + tid] += hv;
    }
    __syncthreads();
    float* dst = pool + (size_t)(blockIdx.x & (NPOOL - 1)) * nb;
    int start = ((int)blockIdx.x * 2048) % nb;  // stagger atomic contention
    for (int t0 = 0; t0 < nb; t0 += 256) {
        int t = (start + t0 + tid) % nb;
        unsafeAtomicAdd(&dst[t], spool[t]);
    }
}

// ---------- mean over comps (sum NPOOL copies), BN over the 64 image rows
__global__ void bn5_kernel(const float* __restrict__ pool,
                           const int* __restrict__ pcnt,
                           const float* __restrict__ g5,
                           const float* __restrict__ be5,
                           float* __restrict__ y, int B) {
    int ch = threadIdx.x;
    int nb = B * 256;
    double s = 0.0, s2 = 0.0;
    float vals[64];
    for (int b = 0; b < B; ++b) {
        float v = 0.f;
        #pragma unroll
        for (int k = 0; k < NPOOL; ++k) v += pool[k * nb + b * 256 + ch];
        float c = (float)pcnt[b]; if (c < 1.f) c = 1.f;
        v /= c;
        vals[b] = v;
        s += (double)v; s2 += (double)v * (double)v;
    }
    double m = s / (double)B;
    double var = s2 / (double)B - m * m;
    float rs = rsqrtf((float)var + BN_EPS);
    float a = g5[ch] * rs;
    float cc = be5[ch] - (float)m * a;
    for (int b = 0; b < B; ++b)
        y[b * 256 + ch] = fmaf(a, vals[b], cc);
}

// ------------------------------------------------------- final FC + ReLU
__global__ __launch_bounds__(256) void fc_kernel(
    const float* __restrict__ y, const float* __restrict__ Wfc,
    const float* __restrict__ bfc, float* __restrict__ out, int NC) {
    int b = blockIdx.y;
    int ch = blockIdx.x * 256 + threadIdx.x;
    __shared__ float sy[256];
    sy[threadIdx.x] = y[b * 256 + threadIdx.x];
    __syncthreads();
    if (ch < NC) {
        float acc = bfc[ch];
        for (int k = 0; k < 256; ++k)
            acc = fmaf(sy[k], Wfc[(size_t)k * NC + ch], acc);
        out[(size_t)b * NC + ch] = fmaxf(acc, 0.f);
    }
}

// ---------------------------------------------------------------- launcher
extern "C" void kernel_launch(void* const* d_in, const int* in_sizes, int n_in,
                              void* d_out, int out_size, void* d_ws,
                              size_t ws_size, hipStream_t stream) {
    const float* item_feat = (const float*)d_in[0];
    const int*   ccids     = (const int*)d_in[1];
    const int*   imgid     = (const int*)d_in[2];
    const float* W1  = (const float*)d_in[3];
    const float* b1  = (const float*)d_in[4];
    const float* g1  = (const float*)d_in[5];
    const float* be1 = (const float*)d_in[6];
    const float* W2  = (const float*)d_in[7];
    const float* b2  = (const float*)d_in[8];
    const float* g2  = (const float*)d_in[9];
    const float* be2 = (const float*)d_in[10];
    const float* W3  = (const float*)d_in[11];
    const float* b3  = (const float*)d_in[12];
    const float* g3  = (const float*)d_in[13];
    const float* be3 = (const float*)d_in[14];
    const float* W4  = (const float*)d_in[15];
    const float* b4  = (const float*)d_in[16];
    const float* g4  = (const float*)d_in[17];
    const float* be4 = (const float*)d_in[18];
    const float* g5  = (const float*)d_in[19];
    const float* be5 = (const float*)d_in[20];
    const float* Wfc = (const float*)d_in[21];
    const float* bfc = (const float*)d_in[22];
    float* out = (float*)d_out;

    const int N  = in_sizes[1];        // 4,000,000 items
    const int C  = in_sizes[2];        // 200,000 components
    const int NC = in_sizes[22];       // 1000 classes
    const int B  = out_size / NC;      // 64 images

    // ---- workspace layout: explicit liveness-based aliasing ----
    uint8_t* ws = (uint8_t*)d_ws;
    size_t off_ = 0;
    auto alloc = [&](size_t bytes) -> void* {
        void* p = (void*)(ws + off_);
        off_ += (bytes + 255) & ~(size_t)255;
        return p;
    };
    int*    cnt    = (int*)alloc((size_t)C * 4);
    double* dstats = (double*)alloc((size_t)(32 + 64 + 128 + 256) * 2 * 8);
    int*    pcnt   = (int*)alloc((size_t)B * 4);
    float*  pool   = (float*)alloc((size_t)NPOOL * B * 256 * 4);  // 1 MB
    size_t zeroBytes = off_;  // accumulated-into region -> zero every call
    float*  y      = (float*)alloc((size_t)B * 256 * 4);
    int*    off    = (int*)alloc((size_t)C * 4);
    int*    woff   = (int*)alloc((size_t)C * 4);
    int*    bsum   = (int*)alloc((size_t)1024 * 4);
    unsigned short* w4t = (unsigned short*)alloc((size_t)256 * 128 * 2);
    unsigned short* w1t = (unsigned short*)alloc((size_t)32 * 352 * 2);
    void* regionA = alloc((size_t)N * 16);        // 64MB: rec -> z1 f32 -> z3 bf16
    void* regionB = alloc((size_t)C * 256 * 2);   // 102.4MB: srec -> z2 -> z4
    (void)ws_size;  // total ~170 MB

    i32x4*           rec    = (i32x4*)regionA;            // N x 16B (dies @scatter)
    float*           z1     = (float*)regionA;            // C x 32 f32
    __hip_bfloat16*  z3     = (__hip_bfloat16*)regionA;   // C x 128 bf16
    i32x4*           srec   = (i32x4*)regionB;            // N x 16B (dies @layer1)
    __hip_bfloat16*  z2     = (__hip_bfloat16*)regionB;   // C x 64 bf16 (after layer1)
    __hip_bfloat16*  z4     = (__hip_bfloat16*)regionB;   // C x 256 bf16 (after z2)

    double *ds1 = dstats +   0, *dq1 = dstats +  32;
    double *ds2 = dstats +  64, *dq2 = dstats + 128;
    double *ds3 = dstats + 192, *dq3 = dstats + 320;
    double *ds4 = dstats + 448, *dq4 = dstats + 704;

    const int nb = (C + 2047) / 2048;  // scan blocks
    const int cg = (C + 7) / 8;        // comps per XCD group

    zero_kernel<<<256, 256, 0, stream>>>((float*)ws, zeroBytes / 4);
    hist_kernel<<<2048, 256, 0, stream>>>((const i32x4*)ccids, cnt, N / 4, cg);
    imgcnt_kernel<<<256, 256, 0, stream>>>(imgid, pcnt, C, B);
    conv_kernel<<<2048, 256, 0, stream>>>(item_feat, rec, N);
    scan_partial<<<nb, 256, 0, stream>>>(cnt, bsum, C);
    scan_tops<<<1, 64, 0, stream>>>(bsum, nb);
    scan_final<<<nb, 256, 0, stream>>>(cnt, bsum, off, woff, C);
    scatter2p_kernel<<<4096, 256, 0, stream>>>((const i32x4*)ccids, rec,
                                               woff, srec, N / 4, cg);
    prep_kernel<<<172, 256, 0, stream>>>(W4, W1, w4t, w1t);

    layer1_mfma<<<(C + 63) / 64, 256, 0, stream>>>(srec, cnt, off,
                                                   w1t, b1, z1, ds1, dq1, C);

    layer_kernel<float, __hip_bfloat16, 32, 64, 4, 8>
        <<<(C + 127) / 128, 256, 0, stream>>>(z1, W2, b2, ds1, dq1, g1, be1,
                                              z2, ds2, dq2, C);
    layer_kernel<__hip_bfloat16, __hip_bfloat16, 64, 128, 4, 8>
        <<<(C + 63) / 64, 256, 0, stream>>>(z2, W3, b3, ds2, dq2, g2, be2,
                                            z3, ds3, dq3, C);
    layer4_mfma<<<(C + 63) / 64, 256, 0, stream>>>(z3, w4t, b4, ds3, dq3,
                                                   g3, be3, z4, ds4, dq4, C);

    pool_kernel<<<256, 256, 0, stream>>>(z4, imgid, ds4, dq4, g4, be4,
                                         pool, C, B);
    bn5_kernel<<<1, 256, 0, stream>>>(pool, pcnt, g5, be5, y, B);

    dim3 fcg((NC + 255) / 256, B);
    fc_kernel<<<fcg, 256, 0, stream>>>(y, Wfc, bfc, out, NC);
}

// Round 14
// 1000.040 us; speedup vs baseline: 1.1770x; 1.1770x over previous
//
#include <hip/hip_runtime.h>
#include <hip/hip_bf16.h>
#include <cstdint>
#include <cstddef>

#define MAX_K 70
#define BN_EPS 1e-5f
#define KPAD 360   // 352 data + 8 pad bf16 -> stride 720B, 2-way max bank alias
#define NPOOL 16   // pool copies to spread atomic contention

typedef __attribute__((ext_vector_type(4))) float f32x4;
typedef __attribute__((ext_vector_type(8))) short bf16x8;
typedef __attribute__((ext_vector_type(4))) int i32x4;

// ---------------- load/store helpers (f32 or bf16 storage) ----------------
__device__ inline float loadv(const float* p, size_t i) { return p[i]; }
__device__ inline float loadv(const __hip_bfloat16* p, size_t i) {
    return __bfloat162float(p[i]);
}
__device__ inline void storev(float* p, size_t i, float v) { p[i] = v; }
__device__ inline void storev(__hip_bfloat16* p, size_t i, float v) {
    p[i] = __float2bfloat16(v);
}
__device__ inline float bf2f(unsigned short u) {
    union { unsigned int i; float f; } x; x.i = ((unsigned int)u) << 16; return x.f;
}
__device__ inline unsigned short f2bfu(float f) {
    __hip_bfloat16 h = __float2bfloat16(f);
    return *reinterpret_cast<unsigned short*>(&h);
}

// ---- per-block BN scale/shift derivation from accumulated sum/sumsq ------
template <int FO>
__device__ inline void bn_make(const double* __restrict__ ds,
                               const double* __restrict__ dq,
                               const float* __restrict__ g,
                               const float* __restrict__ be, int C,
                               float* aSs, float* cSs, int tid) {
    if (tid < FO) {
        double m = ds[tid] / (double)C;
        double v = dq[tid] / (double)C - m * m;
        float rs = rsqrtf((float)v + BN_EPS);
        float a = g[tid] * rs;
        aSs[tid] = a;
        cSs[tid] = be[tid] - (float)m * a;
    }
}

// ---------------------------------------------------------------- utilities
__global__ void zero_kernel(float* __restrict__ p, size_t n) {
    size_t i = (size_t)blockIdx.x * blockDim.x + threadIdx.x;
    size_t stride = (size_t)gridDim.x * blockDim.x;
    for (; i < n; i += stride) p[i] = 0.f;
}

// ---------------- stage 1a: histogram (XCD-partitioned by ccid range) -----
__global__ __launch_bounds__(256) void hist_kernel(
    const i32x4* __restrict__ cc4, int* __restrict__ cnt, int n4, int cg) {
    int g  = blockIdx.x & 7;
    int k  = blockIdx.x >> 3;
    int nk = gridDim.x >> 3;
    int clo = g * cg, chi = clo + cg;
    for (int q = k * 256 + threadIdx.x; q < n4; q += nk * 256) {
        i32x4 v = cc4[q];
        #pragma unroll
        for (int e = 0; e < 4; ++e) {
            int c = v[e];
            if (c >= clo && c < chi) atomicAdd(&cnt[c], 1);
        }
    }
}

// --------------------------------------- stage 1b: exclusive scan over cnt
__global__ __launch_bounds__(256) void scan_partial(const int* __restrict__ cnt,
                                                    int* __restrict__ bsum, int C) {
    __shared__ int sc[256];
    int b = blockIdx.x, tid = threadIdx.x;
    int base = b * 2048 + tid * 8;
    int t = 0;
    #pragma unroll
    for (int e = 0; e < 8; ++e) {
        int c = base + e;
        t += (c < C) ? cnt[c] : 0;
    }
    sc[tid] = t;
    __syncthreads();
    for (int o = 128; o > 0; o >>= 1) {
        if (tid < o) sc[tid] += sc[tid + o];
        __syncthreads();
    }
    if (tid == 0) bsum[b] = sc[0];
}

__global__ void scan_tops(int* __restrict__ bsum, int nb) {
    if (blockIdx.x == 0 && threadIdx.x == 0) {
        int run = 0;
        for (int k = 0; k < nb; ++k) { int t = bsum[k]; bsum[k] = run; run += t; }
    }
}

__global__ __launch_bounds__(256) void scan_final(const int* __restrict__ cnt,
                                                  const int* __restrict__ btop,
                                                  int* __restrict__ off,
                                                  int* __restrict__ woff, int C) {
    __shared__ int sc[256];
    int b = blockIdx.x, tid = threadIdx.x;
    int base = b * 2048 + tid * 8;
    int v[8];
    int tsum = 0;
    #pragma unroll
    for (int e = 0; e < 8; ++e) {
        int c = base + e;
        v[e] = (c < C) ? cnt[c] : 0;
        tsum += v[e];
    }
    sc[tid] = tsum;
    __syncthreads();
    for (int d = 1; d < 256; d <<= 1) {
        int t = (tid >= d) ? sc[tid - d] : 0;
        __syncthreads();
        sc[tid] += t;
        __syncthreads();
    }
    int run = btop[b] + sc[tid] - tsum;
    #pragma unroll
    for (int e = 0; e < 8; ++e) {
        int c = base + e;
        if (c < C) { off[c] = run; woff[c] = run; }
        run += v[e];
    }
}

// ------- prep: feat -> 16B records {idx:int, f0..f4:bf16, pad} (coalesced)
__global__ __launch_bounds__(256) void conv_kernel(
    const float* __restrict__ feat, i32x4* __restrict__ rec, int N) {
    int i = blockIdx.x * 256 + threadIdx.x;
    int stride = gridDim.x * 256;
    for (; i < N; i += stride) {
        const float* fp = &feat[(size_t)i * 5];
        unsigned int h0 = f2bfu(fp[0]), h1 = f2bfu(fp[1]), h2 = f2bfu(fp[2]);
        unsigned int h3 = f2bfu(fp[3]), h4 = f2bfu(fp[4]);
        i32x4 r;
        r[0] = i;
        r[1] = (int)(h0 | (h1 << 16));
        r[2] = (int)(h2 | (h3 << 16));
        r[3] = (int)h4;
        rec[i] = r;
    }
}

// ----- stage 1c: XCD-partitioned counting-sort scatter of 16B records.
// ONE line-touch per item: per-XCD write-head set = C/8 lines = 1.6MB < 4MB
// L2 -> lines fill completely, ~1 writeback each. rec reads served by L3.
__global__ __launch_bounds__(256) void scatter2p_kernel(
    const i32x4* __restrict__ ccids4, const i32x4* __restrict__ rec,
    int* __restrict__ woff, i32x4* __restrict__ srec, int n4, int cg) {
    int g   = blockIdx.x & 7;
    int k   = blockIdx.x >> 3;
    int nk  = gridDim.x >> 3;
    int clo = g * cg, chi = clo + cg;
    for (int q = k * 256 + threadIdx.x; q < n4; q += nk * 256) {
        i32x4 v = ccids4[q];
        int base = q * 4;
        #pragma unroll
        for (int e = 0; e < 4; ++e) {
            int c = v[e];
            if (c >= clo && c < chi) {
                int p = atomicAdd(&woff[c], 1);
                srec[p] = rec[base + e];
            }
        }
    }
}

// ----- prep: W4 -> bf16 w4t[256][128]; W1 -> bf16 w1t[32][352] (transposed)
__global__ void prep_kernel(const float* __restrict__ W4,
                            const float* __restrict__ W1,
                            unsigned short* __restrict__ w4t,
                            unsigned short* __restrict__ w1t) {
    int idx = blockIdx.x * 256 + threadIdx.x;
    if (idx < 32768) {
        int n = idx >> 7, k = idx & 127;
        w4t[idx] = f2bfu(W4[k * 256 + n]);
    } else if (idx < 32768 + 32 * 352) {
        int j = idx - 32768;
        int ch = j / 352, k = j - ch * 352;
        w1t[j] = (k < 350) ? f2bfu(W1[k * 32 + ch]) : 0;
    }
}

// --- stage 1d+2a: rank+pack+MFMA GEMM 350->32, COALESCED reads, BN1 stats --
// 4 waves/block, each wave owns 16 components (one 16-row MFMA A-tile)
__global__ __launch_bounds__(256) void layer1_mfma(
    const i32x4* __restrict__ srec, const int* __restrict__ cnt,
    const int* __restrict__ off,
    const unsigned short* __restrict__ w1t, const float* __restrict__ b1,
    float* __restrict__ z1, double* __restrict__ dsum,
    double* __restrict__ dsq, int C) {
    __shared__ unsigned short xtile[4][16][KPAD];  // 45 KB
    __shared__ float sps[4][32], spq[4][32];
    int tid  = threadIdx.x;
    int w    = tid >> 6;
    int lane = tid & 63;
    int cbase = blockIdx.x * 64 + w * 16;

    // zero my wave's tile
    unsigned int* xz = (unsigned int*)&xtile[w][0][0];
    for (int t = lane; t < 16 * (KPAD / 2); t += 64) xz[t] = 0u;

    // per-sub lengths/bases: lanes 0..15 carry subs 0..15
    int myc = 0, myo = 0;
    {
        int comp = cbase + (lane & 15);
        if (comp < C) { myc = cnt[comp]; myo = off[comp]; }
    }
    int fl[16], bs[16];
    #pragma unroll
    for (int s = 0; s < 16; ++s) {
        fl[s] = __shfl(myc, s);
        bs[s] = __shfl(myo, s);
    }
    // coalesced record loads: idx + feats in ONE int4 per member
    #pragma unroll
    for (int s = 0; s < 16; ++s) {
        if (fl[s] <= 64) {
            i32x4 r;
            int my = 0x7FFFFFFF;
            if (lane < fl[s]) {
                r = srec[bs[s] + lane];
                my = r[0];
            }
            // rank via shfl (VALU only)
            int rk = 0;
            for (int j = 0; j < fl[s]; ++j) {
                int o = __shfl(my, j);
                rk += (o < my) ? 1 : 0;
            }
            if (lane < fl[s]) {
                unsigned short* xp = &xtile[w][s][rk * 5];
                unsigned int y1 = (unsigned int)r[1];
                unsigned int y2 = (unsigned int)r[2];
                unsigned int y3 = (unsigned int)r[3];
                xp[0] = (unsigned short)(y1 & 0xffff);
                xp[1] = (unsigned short)(y1 >> 16);
                xp[2] = (unsigned short)(y2 & 0xffff);
                xp[3] = (unsigned short)(y2 >> 16);
                xp[4] = (unsigned short)(y3 & 0xffff);
            }
        } else {
            // rare fallback (cnt>64): rank via global records
            for (int e = lane; e < fl[s]; e += 64) {
                i32x4 r = srec[bs[s] + e];
                int my = r[0];
                int rk = 0;
                for (int j = 0; j < fl[s]; ++j)
                    rk += (srec[bs[s] + j][0] < my) ? 1 : 0;
                if (rk < MAX_K) {
                    unsigned short* xp = &xtile[w][s][rk * 5];
                    unsigned int y1 = (unsigned int)r[1];
                    unsigned int y2 = (unsigned int)r[2];
                    unsigned int y3 = (unsigned int)r[3];
                    xp[0] = (unsigned short)(y1 & 0xffff);
                    xp[1] = (unsigned short)(y1 >> 16);
                    xp[2] = (unsigned short)(y2 & 0xffff);
                    xp[3] = (unsigned short)(y2 >> 16);
                    xp[4] = (unsigned short)(y3 & 0xffff);
                }
            }
        }
    }
    __syncthreads();  // xtile writes -> cross-lane MFMA fragment reads

    int l15 = lane & 15, l4 = lane >> 4;
    f32x4 acc0 = {0.f, 0.f, 0.f, 0.f};
    f32x4 acc1 = {0.f, 0.f, 0.f, 0.f};
    const unsigned short* xbase = &xtile[w][l15][0];
    #pragma unroll
    for (int ks = 0; ks < 11; ++ks) {
        int k0 = ks * 32 + l4 * 8;
        bf16x8 a  = *(const bf16x8*)&xbase[k0];
        bf16x8 b0 = *(const bf16x8*)&w1t[(size_t)l15 * 352 + k0];
        bf16x8 bv = *(const bf16x8*)&w1t[(size_t)(16 + l15) * 352 + k0];
        acc0 = __builtin_amdgcn_mfma_f32_16x16x32_bf16(a, b0, acc0, 0, 0, 0);
        acc1 = __builtin_amdgcn_mfma_f32_16x16x32_bf16(a, bv, acc1, 0, 0, 0);
    }
    float bias0 = b1[l15];
    float bias1 = b1[16 + l15];
    float s0 = 0.f, q0 = 0.f, s1 = 0.f, q1 = 0.f;
    #pragma unroll
    for (int r = 0; r < 4; ++r) {
        int comp = cbase + l4 * 4 + r;
        if (comp < C) {
            float z0 = acc0[r] + bias0;
            float z1v = acc1[r] + bias1;
            z1[(size_t)comp * 32 + l15]      = z0;
            z1[(size_t)comp * 32 + 16 + l15] = z1v;
            s0 += z0; q0 += z0 * z0;
            s1 += z1v; q1 += z1v * z1v;
        }
    }
    // reduce over the 4 row-groups (lanes same l15, l4 in 0..3)
    s0 += __shfl_xor(s0, 16); s0 += __shfl_xor(s0, 32);
    q0 += __shfl_xor(q0, 16); q0 += __shfl_xor(q0, 32);
    s1 += __shfl_xor(s1, 16); s1 += __shfl_xor(s1, 32);
    q1 += __shfl_xor(q1, 16); q1 += __shfl_xor(q1, 32);
    if (lane < 16) {
        sps[w][l15] = s0;      spq[w][l15] = q0;
        sps[w][16 + l15] = s1; spq[w][16 + l15] = q1;
    }
    __syncthreads();
    if (tid < 32) {
        float s = sps[0][tid] + sps[1][tid] + sps[2][tid] + sps[3][tid];
        float q = spq[0][tid] + spq[1][tid] + spq[2][tid] + spq[3][tid];
        unsafeAtomicAdd(&dsum[tid], (double)s);
        unsafeAtomicAdd(&dsq[tid],  (double)q);
    }
}

// ---- generic layer: zout = relu(bn(zin)) @ W + b, BN derived per block ----
template <typename TI, typename TO, int FI, int FO, int CT, int RT>
__global__ __launch_bounds__(256) void layer_kernel(
    const TI* __restrict__ zin, const float* __restrict__ W,
    const float* __restrict__ bias,
    const double* __restrict__ dsI, const double* __restrict__ dqI,
    const float* __restrict__ g, const float* __restrict__ be,
    TO* __restrict__ zout,
    double* __restrict__ dsO, double* __restrict__ dqO, int C) {
    constexpr int CHG  = FO / CT;
    constexpr int NSUB = 256 / CHG;
    constexpr int R    = NSUB * RT;
    __shared__ float h[R][FI + 1];
    __shared__ float sps[NSUB * FO];
    __shared__ float spq[NSUB * FO];
    __shared__ float aSs[FI], cSs[FI];
    int tid = threadIdx.x;
    int c0 = blockIdx.x * R;
    bn_make<FI>(dsI, dqI, g, be, C, aSs, cSs, tid);
    __syncthreads();
    for (int t = tid; t < R * FI; t += 256) {
        int r = t / FI, k = t % FI;
        int c = c0 + r;
        float v = (c < C) ? loadv(zin, (size_t)c * FI + k) : 0.f;
        h[r][k] = fmaxf(fmaf(aSs[k], v, cSs[k]), 0.f);
    }
    __syncthreads();
    int cg  = tid % CHG;
    int sub = tid / CHG;
    int chbase = cg * CT;
    float acc[RT][CT];
    #pragma unroll
    for (int i = 0; i < RT; ++i)
        #pragma unroll
        for (int j = 0; j < CT; ++j) acc[i][j] = 0.f;
    for (int k = 0; k < FI; ++k) {
        float wv[CT];
        #pragma unroll
        for (int j4 = 0; j4 < CT; j4 += 4) {
            const float4 wq = *reinterpret_cast<const float4*>(
                &W[(size_t)k * FO + chbase + j4]);
            wv[j4 + 0] = wq.x; wv[j4 + 1] = wq.y;
            wv[j4 + 2] = wq.z; wv[j4 + 3] = wq.w;
        }
        #pragma unroll
        for (int i = 0; i < RT; ++i) {
            float hv = h[sub * RT + i][k];
            #pragma unroll
            for (int j = 0; j < CT; ++j) acc[i][j] = fmaf(hv, wv[j], acc[i][j]);
        }
    }
    float ps[CT], pq[CT];
    #pragma unroll
    for (int j = 0; j < CT; ++j) { ps[j] = 0.f; pq[j] = 0.f; }
    #pragma unroll
    for (int i = 0; i < RT; ++i) {
        int c = c0 + sub * RT + i;
        if (c < C) {
            #pragma unroll
            for (int j = 0; j < CT; ++j) {
                float z = acc[i][j] + bias[chbase + j];
                storev(zout, (size_t)c * FO + chbase + j, z);
                ps[j] += z;
                pq[j] += z * z;
            }
        }
    }
    #pragma unroll
    for (int j = 0; j < CT; ++j) {
        sps[sub * FO + chbase + j] = ps[j];
        spq[sub * FO + chbase + j] = pq[j];
    }
    __syncthreads();
    if (tid < FO) {
        float s = 0.f, q = 0.f;
        #pragma unroll
        for (int s2 = 0; s2 < NSUB; ++s2) {
            s += sps[s2 * FO + tid];
            q += spq[s2 * FO + tid];
        }
        unsafeAtomicAdd(&dsO[tid], (double)s);
        unsafeAtomicAdd(&dqO[tid], (double)q);
    }
}

// ------------- layer 4 via MFMA: z4 = relu(bn3(z3)) @ W4 + b4, fused stats
__global__ __launch_bounds__(256) void layer4_mfma(
    const __hip_bfloat16* __restrict__ z3, const unsigned short* __restrict__ w4t,
    const float* __restrict__ b4,
    const double* __restrict__ dsI, const double* __restrict__ dqI,
    const float* __restrict__ g, const float* __restrict__ be,
    __hip_bfloat16* __restrict__ z4,
    double* __restrict__ dsum, double* __restrict__ dsq, int C) {
    __shared__ float sps[2][256];
    __shared__ float spq[2][256];
    __shared__ float aSs[128], cSs[128];
    int tid = threadIdx.x, wid = tid >> 6, lane = tid & 63;
    int wm = wid >> 1, wn = wid & 1;
    int c0 = blockIdx.x * 64;
    int l15 = lane & 15, l4 = lane >> 4;
    const unsigned short* z3u = (const unsigned short*)z3;
    bn_make<128>(dsI, dqI, g, be, C, aSs, cSs, tid);
    __syncthreads();

    f32x4 acc[2][8];
    #pragma unroll
    for (int mi = 0; mi < 2; ++mi)
        #pragma unroll
        for (int ni = 0; ni < 8; ++ni) acc[mi][ni] = (f32x4){0.f, 0.f, 0.f, 0.f};

    int rowA0 = c0 + wm * 32 + l15;
    #pragma unroll
    for (int ks = 0; ks < 4; ++ks) {
        int k0 = ks * 32 + l4 * 8;
        float sc[8], cc[8];
        #pragma unroll
        for (int j = 0; j < 8; ++j) { sc[j] = aSs[k0 + j]; cc[j] = cSs[k0 + j]; }
        bf16x8 afrag[2];
        #pragma unroll
        for (int mi = 0; mi < 2; ++mi) {
            int r = rowA0 + mi * 16;
            int rc = (r < C) ? r : (C - 1);
            bf16x8 raw = *(const bf16x8*)&z3u[(size_t)rc * 128 + k0];
            bf16x8 af;
            #pragma unroll
            for (int j = 0; j < 8; ++j) {
                float v = bf2f((unsigned short)raw[j]);
                float hx = fmaxf(fmaf(sc[j], v, cc[j]), 0.f);
                af[j] = (short)f2bfu((r < C) ? hx : 0.f);
            }
            afrag[mi] = af;
        }
        bf16x8 bfrag[8];
        #pragma unroll
        for (int ni = 0; ni < 8; ++ni) {
            int n = wn * 128 + ni * 16 + l15;
            bfrag[ni] = *(const bf16x8*)&w4t[(size_t)n * 128 + k0];
        }
        #pragma unroll
        for (int mi = 0; mi < 2; ++mi)
            #pragma unroll
            for (int ni = 0; ni < 8; ++ni)
                acc[mi][ni] = __builtin_amdgcn_mfma_f32_16x16x32_bf16(
                    afrag[mi], bfrag[ni], acc[mi][ni], 0, 0, 0);
    }
    unsigned short* z4u = (unsigned short*)z4;
    #pragma unroll
    for (int ni = 0; ni < 8; ++ni) {
        int col = wn * 128 + ni * 16 + l15;
        float bv = b4[col];
        float s = 0.f, q = 0.f;
        #pragma unroll
        for (int mi = 0; mi < 2; ++mi) {
            #pragma unroll
            for (int r = 0; r < 4; ++r) {
                int row = c0 + wm * 32 + mi * 16 + l4 * 4 + r;
                float z = acc[mi][ni][r] + bv;
                if (row < C) {
                    z4u[(size_t)row * 256 + col] = f2bfu(z);
                    s += z;
                    q += z * z;
                }
            }
        }
        s += __shfl_xor(s, 16); s += __shfl_xor(s, 32);
        q += __shfl_xor(q, 16); q += __shfl_xor(q, 32);
        if (lane < 16) { sps[wm][col] = s; spq[wm][col] = q; }
    }
    __syncthreads();
    if (tid < 256) {
        float s = sps[0][tid] + sps[1][tid];
        float q = spq[0][tid] + spq[1][tid];
        unsafeAtomicAdd(&dsum[tid], (double)s);
        unsafeAtomicAdd(&dsq[tid],  (double)q);
    }
}

// ----------------------------------------------- per-image component counts
__global__ void imgcnt_kernel(const int* __restrict__ imgid,
                              int* __restrict__ pcnt, int C, int B) {
    __shared__ int scnt[64];
    int tid = threadIdx.x;
    if (tid < B) scnt[tid] = 0;
    __syncthreads();
    for (int i = blockIdx.x * 256 + tid; i < C; i += gridDim.x * 256)
        atomicAdd(&scnt[imgid[i]], 1);
    __syncthreads();
    if (tid < B) atomicAdd(&pcnt[tid], scnt[tid]);
}

// -- segment-sum of relu(bn4(z4)) into NPOOL pool copies; unroll-8 deep MLP
__global__ __launch_bounds__(256) void pool_kernel(
    const __hip_bfloat16* __restrict__ z4, const int* __restrict__ imgid,
    const double* __restrict__ dsI, const double* __restrict__ dqI,
    const float* __restrict__ g, const float* __restrict__ be,
    float* __restrict__ pool, int C, int B) {
    __shared__ float spool[64 * 256];
    __shared__ float aSs[256], cSs[256];
    int tid = threadIdx.x;
    int nb = B * 256;
    bn_make<256>(dsI, dqI, g, be, C, aSs, cSs, tid);
    for (int t = tid; t < nb; t += 256) spool[t] = 0.f;
    __syncthreads();
    float a = aSs[tid], cc = cSs[tid];
    int per  = (C + gridDim.x - 1) / gridDim.x;
    int cbeg = blockIdx.x * per;
    int cend = min(cbeg + per, C);
    int c = cbeg;
    for (; c + 8 <= cend; c += 8) {
        float v[8];
        int im[8];
        #pragma unroll
        for (int u = 0; u < 8; ++u) {
            im[u] = imgid[c + u];
            v[u] = loadv(z4, (size_t)(c + u) * 256 + tid);
        }
        #pragma unroll
        for (int u = 0; u < 8; ++u) {
            float hv = fmaxf(fmaf(a, v[u], cc), 0.f);
            spool[im[u] * 256 + tid] += hv;
        }
    }
    for (; c < cend; ++c) {
        int img = imgid[c];
        float v = loadv(z4, (size_t)c * 256 + tid);
        float hv = fmaxf(fmaf(a, v, cc), 0.f);
        spool[img * 256 + tid] += hv;
    }
    __syncthreads();
    float* dst = pool + (size_t)(blockIdx.x & (NPOOL - 1)) * nb;
    int start = ((int)blockIdx.x * 2048) % nb;  // stagger atomic contention
    for (int t0 = 0; t0 < nb; t0 += 256) {
        int t = (start + t0 + tid) % nb;
        unsafeAtomicAdd(&dst[t], spool[t]);
    }
}

// ---------- mean over comps (sum NPOOL copies), BN over the 64 image rows
__global__ void bn5_kernel(const float* __restrict__ pool,
                           const int* __restrict__ pcnt,
                           const float* __restrict__ g5,
                           const float* __restrict__ be5,
                           float* __restrict__ y, int B) {
    int ch = threadIdx.x;
    int nb = B * 256;
    double s = 0.0, s2 = 0.0;
    float vals[64];
    for (int b = 0; b < B; ++b) {
        float v = 0.f;
        #pragma unroll
        for (int k = 0; k < NPOOL; ++k) v += pool[k * nb + b * 256 + ch];
        float c = (float)pcnt[b]; if (c < 1.f) c = 1.f;
        v /= c;
        vals[b] = v;
        s += (double)v; s2 += (double)v * (double)v;
    }
    double m = s / (double)B;
    double var = s2 / (double)B - m * m;
    float rs = rsqrtf((float)var + BN_EPS);
    float a = g5[ch] * rs;
    float cc = be5[ch] - (float)m * a;
    for (int b = 0; b < B; ++b)
        y[b * 256 + ch] = fmaf(a, vals[b], cc);
}

// ------------------------------------------------------- final FC + ReLU
__global__ __launch_bounds__(256) void fc_kernel(
    const float* __restrict__ y, const float* __restrict__ Wfc,
    const float* __restrict__ bfc, float* __restrict__ out, int NC) {
    int b = blockIdx.y;
    int ch = blockIdx.x * 256 + threadIdx.x;
    __shared__ float sy[256];
    sy[threadIdx.x] = y[b * 256 + threadIdx.x];
    __syncthreads();
    if (ch < NC) {
        float acc = bfc[ch];
        for (int k = 0; k < 256; ++k)
            acc = fmaf(sy[k], Wfc[(size_t)k * NC + ch], acc);
        out[(size_t)b * NC + ch] = fmaxf(acc, 0.f);
    }
}

// ---------------------------------------------------------------- launcher
extern "C" void kernel_launch(void* const* d_in, const int* in_sizes, int n_in,
                              void* d_out, int out_size, void* d_ws,
                              size_t ws_size, hipStream_t stream) {
    const float* item_feat = (const float*)d_in[0];
    const int*   ccids     = (const int*)d_in[1];
    const int*   imgid     = (const int*)d_in[2];
    const float* W1  = (const float*)d_in[3];
    const float* b1  = (const float*)d_in[4];
    const float* g1  = (const float*)d_in[5];
    const float* be1 = (const float*)d_in[6];
    const float* W2  = (const float*)d_in[7];
    const float* b2  = (const float*)d_in[8];
    const float* g2  = (const float*)d_in[9];
    const float* be2 = (const float*)d_in[10];
    const float* W3  = (const float*)d_in[11];
    const float* b3  = (const float*)d_in[12];
    const float* g3  = (const float*)d_in[13];
    const float* be3 = (const float*)d_in[14];
    const float* W4  = (const float*)d_in[15];
    const float* b4  = (const float*)d_in[16];
    const float* g4  = (const float*)d_in[17];
    const float* be4 = (const float*)d_in[18];
    const float* g5  = (const float*)d_in[19];
    const float* be5 = (const float*)d_in[20];
    const float* Wfc = (const float*)d_in[21];
    const float* bfc = (const float*)d_in[22];
    float* out = (float*)d_out;

    const int N  = in_sizes[1];        // 4,000,000 items
    const int C  = in_sizes[2];        // 200,000 components
    const int NC = in_sizes[22];       // 1000 classes
    const int B  = out_size / NC;      // 64 images

    // ---- workspace layout: explicit liveness-based aliasing ----
    uint8_t* ws = (uint8_t*)d_ws;
    size_t off_ = 0;
    auto alloc = [&](size_t bytes) -> void* {
        void* p = (void*)(ws + off_);
        off_ += (bytes + 255) & ~(size_t)255;
        return p;
    };
    int*    cnt    = (int*)alloc((size_t)C * 4);
    double* dstats = (double*)alloc((size_t)(32 + 64 + 128 + 256) * 2 * 8);
    int*    pcnt   = (int*)alloc((size_t)B * 4);
    float*  pool   = (float*)alloc((size_t)NPOOL * B * 256 * 4);  // 1 MB
    size_t zeroBytes = off_;  // accumulated-into region -> zero every call
    float*  y      = (float*)alloc((size_t)B * 256 * 4);
    int*    off    = (int*)alloc((size_t)C * 4);
    int*    woff   = (int*)alloc((size_t)C * 4);
    int*    bsum   = (int*)alloc((size_t)1024 * 4);
    unsigned short* w4t = (unsigned short*)alloc((size_t)256 * 128 * 2);
    unsigned short* w1t = (unsigned short*)alloc((size_t)32 * 352 * 2);
    void* regionA = alloc((size_t)N * 16);        // 64MB: rec -> z1 f32 -> z3 bf16
    void* regionB = alloc((size_t)C * 256 * 2);   // 102.4MB: srec -> z2 -> z4
    (void)ws_size;  // total ~170 MB

    i32x4*           rec    = (i32x4*)regionA;            // N x 16B (dies @scatter)
    float*           z1     = (float*)regionA;            // C x 32 f32
    __hip_bfloat16*  z3     = (__hip_bfloat16*)regionA;   // C x 128 bf16
    i32x4*           srec   = (i32x4*)regionB;            // N x 16B (dies @layer1)
    __hip_bfloat16*  z2     = (__hip_bfloat16*)regionB;   // C x 64 bf16 (after layer1)
    __hip_bfloat16*  z4     = (__hip_bfloat16*)regionB;   // C x 256 bf16 (after z2)

    double *ds1 = dstats +   0, *dq1 = dstats +  32;
    double *ds2 = dstats +  64, *dq2 = dstats + 128;
    double *ds3 = dstats + 192, *dq3 = dstats + 320;
    double *ds4 = dstats + 448, *dq4 = dstats + 704;

    const int nb = (C + 2047) / 2048;  // scan blocks
    const int cg = (C + 7) / 8;        // comps per XCD group

    zero_kernel<<<256, 256, 0, stream>>>((float*)ws, zeroBytes / 4);
    hist_kernel<<<2048, 256, 0, stream>>>((const i32x4*)ccids, cnt, N / 4, cg);
    imgcnt_kernel<<<256, 256, 0, stream>>>(imgid, pcnt, C, B);
    conv_kernel<<<2048, 256, 0, stream>>>(item_feat, rec, N);
    scan_partial<<<nb, 256, 0, stream>>>(cnt, bsum, C);
    scan_tops<<<1, 64, 0, stream>>>(bsum, nb);
    scan_final<<<nb, 256, 0, stream>>>(cnt, bsum, off, woff, C);
    scatter2p_kernel<<<2048, 256, 0, stream>>>((const i32x4*)ccids, rec,
                                               woff, srec, N / 4, cg);
    prep_kernel<<<172, 256, 0, stream>>>(W4, W1, w4t, w1t);

    layer1_mfma<<<(C + 63) / 64, 256, 0, stream>>>(srec, cnt, off,
                                                   w1t, b1, z1, ds1, dq1, C);

    layer_kernel<float, __hip_bfloat16, 32, 64, 4, 8>
        <<<(C + 127) / 128, 256, 0, stream>>>(z1, W2, b2, ds1, dq1, g1, be1,
                                              z2, ds2, dq2, C);
    layer_kernel<__hip_bfloat16, __hip_bfloat16, 64, 128, 4, 8>
        <<<(C + 63) / 64, 256, 0, stream>>>(z2, W3, b3, ds2, dq2, g2, be2,
                                            z3, ds3, dq3, C);
    layer4_mfma<<<(C + 63) / 64, 256, 0, stream>>>(z3, w4t, b4, ds3, dq3,
                                                   g3, be3, z4, ds4, dq4, C);

    pool_kernel<<<512, 256, 0, stream>>>(z4, imgid, ds4, dq4, g4, be4,
                                         pool, C, B);
    bn5_kernel<<<1, 256, 0, stream>>>(pool, pcnt, g5, be5, y, B);

    dim3 fcg((NC + 255) / 256, B);
    fc_kernel<<<fcg, 256, 0, stream>>>(y, Wfc, bfc, out, NC);
}